// Round 4
// baseline (4174.316 us; speedup 1.0000x reference)
//
#include <hip/hip_runtime.h>

typedef unsigned short ushort_t;
typedef unsigned int   uint32;
typedef unsigned long long ull_t;
typedef __attribute__((ext_vector_type(8))) short short8;   // 8 x bf16 (4 VGPRs)
typedef __attribute__((ext_vector_type(4))) float floatx4;  // MFMA 16x16 accum

#define B_    32
#define T_    512
#define H_    1024
#define G4_   4096
#define HSEQ_ (B_*T_*H_)     // 16777216

#define NBLK 64

// ---- ws layout, xproj path (requires ws_size >= WS_NEED) ----
#define XPROJ_OFF 0ul                 // bf16 [16384][4096] = 134217728
#define WTIH_OFF  134217728ul         // bf16 [4096][1024]  = 8388608 (dead after
                                      //   gemm_xproj -> reused for tagged h bufs)
#define WTHH_OFF  142606336ul         // bf16 [4096][1024]  = 8388608
#define H0T_OFF   WTIH_OFF            // ull [16384] tagged h, 131072 B
#define H1T_OFF   (WTIH_OFF + 131072ul)
#define WS_NEED   151130112ul         // unchanged from prior rounds

// ---- ws layout, fallback path (R4) ----
#define H0_OFF  0ul
#define H1_OFF  65536ul
#define CTR_OFF 131072ul

__device__ __forceinline__ ushort_t f2b_rne(float f) {
    uint32 u = __float_as_uint(f);
    u += 0x7fffu + ((u >> 16) & 1u);      // round-to-nearest-even
    return (ushort_t)(u >> 16);
}
__device__ __forceinline__ float b2f(ushort_t u) { return __uint_as_float(((uint32)u) << 16); }
__device__ __forceinline__ float sigm(float x)  { return 1.f / (1.f + __expf(-x)); }
__device__ __forceinline__ float tanh_(float x) { return 1.f - 2.f / (__expf(2.f * x) + 1.f); }

// ---------------------------------------------------------------------------
// Transpose+convert: in fp32 [1024 k][4096 n] -> out bf16 [4096 n][1024 k].
// ---------------------------------------------------------------------------
__global__ void transpose_cvt(const float* __restrict__ in, ushort_t* __restrict__ out)
{
    const int id = blockIdx.x * 256 + threadIdx.x;    // 524288 total
    const int n  = id & 4095;
    const int k0 = (id >> 12) * 8;
    union { ushort_t v[8]; uint4 q; } r;
#pragma unroll
    for (int j = 0; j < 8; j++)
        r.v[j] = f2b_rne(in[(size_t)(k0 + j) * G4_ + n]);
    *(uint4*)(out + (size_t)n * 1024 + k0) = r.q;
}

// ---------------------------------------------------------------------------
// xproj GEMM: xproj[m][n] = bf16( sum_k x[m][k]*W_ih[k][n] + bias[n] )
// ---------------------------------------------------------------------------
__launch_bounds__(256, 2)
__global__ void gemm_xproj(const float* __restrict__ A, const ushort_t* __restrict__ Bt,
                           const float* __restrict__ bias, ushort_t* __restrict__ C)
{
    __shared__ ushort_t As[128 * 32];
    __shared__ ushort_t Bs[128 * 32];
    const int tid = threadIdx.x;
    const int wave = tid >> 6, lane = tid & 63, l16 = lane & 15, quad = lane >> 4;
    const int wm = (wave >> 1) * 64, wn = (wave & 1) * 64;
    const int m0 = blockIdx.y * 128, n0 = blockIdx.x * 128;
    const int r = tid >> 2;               // 0..63 (staging row)
    const int kp = (tid & 3) * 8;         // 0..24 step 8

    floatx4 acc[4][4];
#pragma unroll
    for (int i = 0; i < 4; i++)
#pragma unroll
        for (int j = 0; j < 4; j++) acc[i][j] = (floatx4){0.f, 0.f, 0.f, 0.f};

    for (int kk = 0; kk < 1024; kk += 32) {
#pragma unroll
        for (int h = 0; h < 2; h++) {
            const float* ap = A + (size_t)(m0 + r + h * 64) * 1024 + kk + kp;
            const uint4 u0 = *(const uint4*)ap;
            const uint4 u1 = *(const uint4*)(ap + 4);
            uint4 p;
            p.x = __builtin_amdgcn_perm(u0.y, u0.x, 0x07060302u);
            p.y = __builtin_amdgcn_perm(u0.w, u0.z, 0x07060302u);
            p.z = __builtin_amdgcn_perm(u1.y, u1.x, 0x07060302u);
            p.w = __builtin_amdgcn_perm(u1.w, u1.z, 0x07060302u);
            *(uint4*)&As[(r + h * 64) * 32 + kp] = p;
        }
        const ushort_t* bp = Bt + (size_t)(n0 + r) * 1024 + kk + kp;
        *(uint4*)&Bs[r * 32 + kp]        = *(const uint4*)bp;
        *(uint4*)&Bs[(r + 64) * 32 + kp] = *(const uint4*)(bp + 64 * 1024);
        __syncthreads();

        short8 af[4], bfr[4];
#pragma unroll
        for (int i = 0; i < 4; i++) af[i]  = *(const short8*)&As[(wm + i * 16 + l16) * 32 + quad * 8];
#pragma unroll
        for (int j = 0; j < 4; j++) bfr[j] = *(const short8*)&Bs[(wn + j * 16 + l16) * 32 + quad * 8];
#pragma unroll
        for (int i = 0; i < 4; i++)
#pragma unroll
            for (int j = 0; j < 4; j++)
                acc[i][j] = __builtin_amdgcn_mfma_f32_16x16x32_bf16(af[i], bfr[j], acc[i][j], 0, 0, 0);
        __syncthreads();
    }

#pragma unroll
    for (int i = 0; i < 4; i++) {
        const int gm = m0 + wm + i * 16 + quad * 4;
#pragma unroll
        for (int j = 0; j < 4; j++) {
            const int gn = n0 + wn + j * 16 + l16;
            const float bv = bias[gn];
#pragma unroll
            for (int rr = 0; rr < 4; rr++)
                C[(size_t)(gm + rr) * G4_ + gn] = f2b_rne(acc[i][j][rr] + bv);
        }
    }
}

// ---------------------------------------------------------------------------
// Scan v7 (xproj path). 64 blocks x 512 thr (8 waves). v5 compute structure
// (K-half waves: gate g=w&3, K-half kh=w>>2, 16 reg W_hh frags) + SELF-TAGGING
// h exchange -- flags deleted:
//   * h is published as ull words: (h_ej | h_{ej+1}<<16 | (t+1)<<32). Aligned
//     8B stores are single-copy atomic; every word is self-describing, so NO
//     producer-side vmcnt drain, NO flag store, NO flag poll. The 4-round-trip
//     publish chain collapses to store-visible + data-poll.
//   * Consumers poll the data directly: issue all 32 u64 agent-loads (= the
//     full stage for this wave's 8 source blocks), check 32 tags in-register,
//     retry if any stale. On success, strip tags and write the XOR-swizzled
//     LDS bf16 image (identical layout to v5 -> GEMM untouched).
//   * Safety by induction: a block passes its step-t poll only after all 64
//     blocks published h_t, which implies all finished reading h_{t-1}; the
//     t+1 write (same parity buffer as t-1) happens after sync, so no overwrite
//     race. Tag uniqueness: buffer parity alternates, stale tag = t-2 != t.
//   * Tagged buffers (2 x 128KB) live in the dead wtih region (memset AFTER
//     gemm_xproj in-stream), so WS_NEED is unchanged.
// ---------------------------------------------------------------------------
__launch_bounds__(512, 2)
__global__ void lstm_scan_xp(const ushort_t* __restrict__ xproj, // [16384][4096] bf16
                             const ushort_t* __restrict__ wthh,  // [4096][1024] bf16
                             ull_t* __restrict__ h0buf,          // tagged h, parity 0
                             ull_t* __restrict__ h1buf,          // tagged h, parity 1
                             float* __restrict__ out)            // f32: hseq|h_T|c_T
{
    const int tid  = threadIdx.x;
    const int bid  = blockIdx.x;
    const int wave = tid >> 6, lane = tid & 63, l16 = lane & 15, quad = lane >> 4;
    const int g     = wave & 3;
    const int khalf = wave >> 2;
    const int unit0 = bid * 16;
    const int col0  = g * 1024 + unit0 + l16;

    __shared__ ushort_t hs[32 * 1024];   // staged h-state, XOR-swizzled (64 KB)
    __shared__ float gA[4 * 32 * 17];
    __shared__ float gB[4 * 32 * 17];

    // one-time: W_hh B-frags from transposed bf16 weights (16B vector loads)
    short8 whf[16];
#pragma unroll
    for (int kk = 0; kk < 16; kk++)
        whf[kk] = *(const short8*)(wthh + (size_t)col0 * 1024 + khalf * 512 + kk * 32 + quad * 8);

    const int eb = tid >> 4, ej = tid & 15;
    // tagged-word index for this thread's (even) pair
    const int hw64 = (bid >> 1) * 512 + eb * 16 + (bid & 1) * 8 + (ej >> 1);
    float cst = 0.f;

    // swizzled LDS byte offsets for the two A-frag reads of this lane
    const int b0 = l16, b1 = l16 + 16;
    const int off0 = (b0 * 64 + quad * 16) ^ ((b0 & 7) << 4);
    const int off1 = (b1 * 64 + quad * 16) ^ ((b1 & 7) << 4);
    const int rowbase = khalf * 16 * 2048;   // byte offset of this wave's K-half

    // staging geometry: wave w stages source blocks [8w, 8w+8).
    // lane -> (batch seb = lane>>1, unit-half shalf = lane&1); per src:
    // 4 consecutive u64 at (S>>1)*512 + seb*16 + (S&1)*8 + shalf*4.
    const int src0  = wave * 8;
    const int seb   = lane >> 1;
    const int shalf = lane & 1;

    // prefetch xproj gate values for t=0
    ushort_t xq[4];
    {
        const ushort_t* xp = xproj + ((size_t)eb * T_ + 0) * G4_ + unit0 + ej;
#pragma unroll
        for (int gg = 0; gg < 4; gg++) xq[gg] = xp[gg * 1024];
    }

    for (int t = 0; t < 512; t++) {
        const ull_t* hr = (t & 1) ? h1buf : h0buf;
        ull_t*       hw = (t & 1) ? h0buf : h1buf;

        // ---- 1. stage-with-poll: load all 32 tagged u64s, retry until
        //         every tag == t (typ. 1 iteration). This IS the stage.
        ull_t d[8][4];
        {
            const uint32 tg = (uint32)t;
            for (;;) {
#pragma unroll
                for (int sl = 0; sl < 8; sl++) {
                    const int S = src0 + sl;
                    const ull_t* p = hr + (size_t)((S >> 1) * 512 + seb * 16 + (S & 1) * 8 + shalf * 4);
#pragma unroll
                    for (int q = 0; q < 4; q++)
                        d[sl][q] = __hip_atomic_load(p + q,
                                       __ATOMIC_RELAXED, __HIP_MEMORY_SCOPE_AGENT);
                }
                uint32 bad = 0;
#pragma unroll
                for (int sl = 0; sl < 8; sl++)
#pragma unroll
                    for (int q = 0; q < 4; q++)
                        bad |= (uint32)(d[sl][q] >> 32) ^ tg;
                if (__ballot(bad == 0) == ~0ull) break;
            }
        }
        // strip tags -> XOR-swizzled LDS bf16 image (same layout as v5)
#pragma unroll
        for (int sl = 0; sl < 8; sl++) {
            const int S = src0 + sl;
            const int c = ((S >> 1) * 2048 + (S & 1) * 32 + seb * 64 + shalf * 16) >> 4;
            const int dst = (c * 16) ^ (((c >> 2) & 7) << 4);
            uint4 v;
            v.x = (uint32)d[sl][0];
            v.y = (uint32)d[sl][1];
            v.z = (uint32)d[sl][2];
            v.w = (uint32)d[sl][3];
            *(uint4*)((char*)hs + dst) = v;
        }
        __syncthreads();   // sync #1: hs fully staged

        // ---- 2. h-GEMM from LDS (bank-uniform ds_read_b128)
        floatx4 a0a = (floatx4){0.f, 0.f, 0.f, 0.f};
        floatx4 a0b = a0a, a1a = a0a, a1b = a0a;
#pragma unroll
        for (int kk = 0; kk < 16; kk++) {
            const char* base = (const char*)hs + rowbase + kk * 2048;
            const short8 a0 = *(const short8*)(base + off0);
            const short8 a1 = *(const short8*)(base + off1);
            if (kk & 1) {
                a0b = __builtin_amdgcn_mfma_f32_16x16x32_bf16(a0, whf[kk], a0b, 0, 0, 0);
                a1b = __builtin_amdgcn_mfma_f32_16x16x32_bf16(a1, whf[kk], a1b, 0, 0, 0);
            } else {
                a0a = __builtin_amdgcn_mfma_f32_16x16x32_bf16(a0, whf[kk], a0a, 0, 0, 0);
                a1a = __builtin_amdgcn_mfma_f32_16x16x32_bf16(a1, whf[kk], a1a, 0, 0, 0);
            }
        }
        const floatx4 s0 = a0a + a0b;
        const floatx4 s1 = a1a + a1b;
        float* gd = khalf ? gB : gA;
#pragma unroll
        for (int rr = 0; rr < 4; rr++) {
            gd[(g * 32 + quad * 4 + rr) * 17 + l16]      = s0[rr];
            gd[(g * 32 + 16 + quad * 4 + rr) * 17 + l16] = s1[rr];
        }
        __syncthreads();   // sync #2: gate partials exchanged

        // ---- 3. elementwise: thread -> (batch eb, unit ej)
        float hval, cval;
        {
            const float gi = gA[(0 * 32 + eb) * 17 + ej] + gB[(0 * 32 + eb) * 17 + ej] + b2f(xq[0]);
            const float gf = gA[(1 * 32 + eb) * 17 + ej] + gB[(1 * 32 + eb) * 17 + ej] + b2f(xq[1]);
            const float gg = gA[(2 * 32 + eb) * 17 + ej] + gB[(2 * 32 + eb) * 17 + ej] + b2f(xq[2]);
            const float go = gA[(3 * 32 + eb) * 17 + ej] + gB[(3 * 32 + eb) * 17 + ej] + b2f(xq[3]);
            const float iv = sigm(gi);
            const float fv = sigm(gf);
            const float gv = tanh_(gg);
            const float ov = sigm(go);
            cval = fv * cst + iv * gv;
            cst = cval;
            hval = ov * tanh_(cval);
        }

        if (t < 511) {
            // publish tagged pair IMMEDIATELY (critical path); no drain needed
            {
                const uint32 myb = (uint32)f2b_rne(hval);
                const uint32 nbb = (uint32)__shfl_xor((int)myb, 1);
                if ((ej & 1) == 0) {
                    const ull_t pk = (ull_t)(myb | (nbb << 16))
                                   | ((ull_t)(uint32)(t + 1) << 32);
                    __hip_atomic_store(hw + hw64, pk,
                                       __ATOMIC_RELAXED, __HIP_MEMORY_SCOPE_AGENT);
                }
            }
            // off-path work: hseq store + next-step xproj prefetch
            out[((size_t)eb * T_ + t) * H_ + unit0 + ej] = hval;
            {
                const ushort_t* xp = xproj + ((size_t)eb * T_ + (t + 1)) * G4_ + unit0 + ej;
#pragma unroll
                for (int gg = 0; gg < 4; gg++) xq[gg] = xp[gg * 1024];
            }
        } else {
            out[((size_t)eb * T_ + t) * H_ + unit0 + ej] = hval;
            out[HSEQ_ + eb * H_ + unit0 + ej] = hval;
            out[HSEQ_ + B_ * H_ + eb * H_ + unit0 + ej] = cval;
        }
    }
}

// ---------------------------------------------------------------------------
// Fallback (ws too small for xproj): R4 kernel, verbatim.
// ---------------------------------------------------------------------------
__launch_bounds__(512, 2)
__global__ void lstm_scan_fused(const float* __restrict__ x,
                                const float* __restrict__ wih,
                                const float* __restrict__ whh,
                                const float* __restrict__ bias,
                                ushort_t* __restrict__ h0buf,
                                ushort_t* __restrict__ h1buf,
                                float* __restrict__ out,
                                uint32* __restrict__ ctr)
{
    const int tid  = threadIdx.x;
    const int bid  = blockIdx.x;
    const int wave = tid >> 6, lane = tid & 63, l16 = lane & 15, quad = lane >> 4;
    const int g     = wave & 3;
    const int khalf = wave >> 2;
    const int unit0 = bid * 16;
    const int col0  = g * 1024 + unit0 + l16;
    const int kbase = khalf * 512;

    __shared__ ushort_t xs[32 * 1024];
    __shared__ float gA[4 * 32 * 17];
    __shared__ float gB[4 * 32 * 17];

    short8 wif[16], whf[16];
#pragma unroll
    for (int kk = 0; kk < 16; kk++) {
        short8 vi, vh;
#pragma unroll
        for (int j = 0; j < 8; j++) {
            const size_t k = (size_t)(kbase + kk * 32 + quad * 8 + j);
            vi[j] = (short)f2b_rne(wih[k * G4_ + col0]);
            vh[j] = (short)f2b_rne(whh[k * G4_ + col0]);
        }
        wif[kk] = vi;
        whf[kk] = vh;
    }
    const float bcol = (khalf == 0) ? bias[col0] : 0.f;

    const int eb = tid >> 4, ej = tid & 15;
    const int hwoff = (bid >> 1) * 1024 + eb * 32 + 16 * (bid & 1) + ej;
    float cst = 0.f;

    floatx4 a0a, a0b, a1a, a1b;

    {
        const int sb = tid >> 4, sc = tid & 15;
        const float* xrow = x + ((size_t)sb * T_ + 0) * H_ + sc * 64;
#pragma unroll
        for (int q = 0; q < 8; q++) {
            const uint4 u0 = *(const uint4*)(xrow + q * 8);
            const uint4 u1 = *(const uint4*)(xrow + q * 8 + 4);
            uint4 p;
            p.x = __builtin_amdgcn_perm(u0.y, u0.x, 0x07060302u);
            p.y = __builtin_amdgcn_perm(u0.w, u0.z, 0x07060302u);
            p.z = __builtin_amdgcn_perm(u1.y, u1.x, 0x07060302u);
            p.w = __builtin_amdgcn_perm(u1.w, u1.z, 0x07060302u);
            const int k = sc * 64 + q * 8;
            *(uint4*)&xs[(k >> 5) * 1024 + sb * 32 + (k & 31)] = p;
        }
    }
    __syncthreads();
    a0a = (floatx4){bcol, bcol, bcol, bcol};
    a1a = a0a;
    a0b = (floatx4){0.f, 0.f, 0.f, 0.f};
    a1b = a0b;
#pragma unroll
    for (int kk = 0; kk < 16; kk++) {
        const ushort_t* ps = &xs[(khalf * 16 + kk) * 1024 + quad * 8];
        const short8 a0 = *(const short8*)(ps + l16 * 32);
        const short8 a1 = *(const short8*)(ps + (16 + l16) * 32);
        if (kk & 1) {
            a0b = __builtin_amdgcn_mfma_f32_16x16x32_bf16(a0, wif[kk], a0b, 0, 0, 0);
            a1b = __builtin_amdgcn_mfma_f32_16x16x32_bf16(a1, wif[kk], a1b, 0, 0, 0);
        } else {
            a0a = __builtin_amdgcn_mfma_f32_16x16x32_bf16(a0, wif[kk], a0a, 0, 0, 0);
            a1a = __builtin_amdgcn_mfma_f32_16x16x32_bf16(a1, wif[kk], a1a, 0, 0, 0);
        }
    }

    for (int t = 0; t < 512; t++) {
        const ushort_t* hr = (t & 1) ? h1buf : h0buf;
        ushort_t*       hw = (t & 1) ? h0buf : h1buf;

#pragma unroll
        for (int kk = 0; kk < 16; kk++) {
            const ushort_t* pa = hr + (khalf * 16 + kk) * 1024 + quad * 8;
            const short8 a0 = *(const short8*)(pa + l16 * 32);
            const short8 a1 = *(const short8*)(pa + (16 + l16) * 32);
            if (kk & 1) {
                a0b = __builtin_amdgcn_mfma_f32_16x16x32_bf16(a0, whf[kk], a0b, 0, 0, 0);
                a1b = __builtin_amdgcn_mfma_f32_16x16x32_bf16(a1, whf[kk], a1b, 0, 0, 0);
            } else {
                a0a = __builtin_amdgcn_mfma_f32_16x16x32_bf16(a0, whf[kk], a0a, 0, 0, 0);
                a1a = __builtin_amdgcn_mfma_f32_16x16x32_bf16(a1, whf[kk], a1a, 0, 0, 0);
            }
        }
        const floatx4 s0 = a0a + a0b;
        const floatx4 s1 = a1a + a1b;
        float* gd = khalf ? gB : gA;
#pragma unroll
        for (int rr = 0; rr < 4; rr++) {
            gd[(g * 32 + quad * 4 + rr) * 17 + l16]      = s0[rr];
            gd[(g * 32 + 16 + quad * 4 + rr) * 17 + l16] = s1[rr];
        }
        __syncthreads();

        {
            const float gi = gA[(0 * 32 + eb) * 17 + ej] + gB[(0 * 32 + eb) * 17 + ej];
            const float gf = gA[(1 * 32 + eb) * 17 + ej] + gB[(1 * 32 + eb) * 17 + ej];
            const float gg = gA[(2 * 32 + eb) * 17 + ej] + gB[(2 * 32 + eb) * 17 + ej];
            const float go = gA[(3 * 32 + eb) * 17 + ej] + gB[(3 * 32 + eb) * 17 + ej];
            const float iv = sigm(gi);
            const float fv = sigm(gf);
            const float gv = tanh_(gg);
            const float ov = sigm(go);
            const float c = fv * cst + iv * gv;
            cst = c;
            const float h = ov * tanh_(c);
            hw[hwoff] = f2b_rne(h);
            out[((size_t)eb * T_ + t) * H_ + unit0 + ej] = h;
            if (t == 511) {
                out[HSEQ_ + eb * H_ + unit0 + ej] = h;
                out[HSEQ_ + B_ * H_ + eb * H_ + unit0 + ej] = cst;
            }
        }
        __syncthreads();

        if (t < 511) {
            if (tid == 0) {
                __threadfence();
                __hip_atomic_fetch_add(ctr, 1u, __ATOMIC_RELAXED, __HIP_MEMORY_SCOPE_AGENT);
            }
            {
                const int sb = tid >> 4, sc = tid & 15;
                const float* xrow = x + ((size_t)sb * T_ + (t + 1)) * H_ + sc * 64;
#pragma unroll
                for (int q = 0; q < 8; q++) {
                    const uint4 u0 = *(const uint4*)(xrow + q * 8);
                    const uint4 u1 = *(const uint4*)(xrow + q * 8 + 4);
                    uint4 p;
                    p.x = __builtin_amdgcn_perm(u0.y, u0.x, 0x07060302u);
                    p.y = __builtin_amdgcn_perm(u0.w, u0.z, 0x07060302u);
                    p.z = __builtin_amdgcn_perm(u1.y, u1.x, 0x07060302u);
                    p.w = __builtin_amdgcn_perm(u1.w, u1.z, 0x07060302u);
                    const int k = sc * 64 + q * 8;
                    *(uint4*)&xs[(k >> 5) * 1024 + sb * 32 + (k & 31)] = p;
                }
            }
            __syncthreads();
            a0a = (floatx4){bcol, bcol, bcol, bcol};
            a1a = a0a;
            a0b = (floatx4){0.f, 0.f, 0.f, 0.f};
            a1b = a0b;
#pragma unroll
            for (int kk = 0; kk < 16; kk++) {
                const ushort_t* ps = &xs[(khalf * 16 + kk) * 1024 + quad * 8];
                const short8 a0 = *(const short8*)(ps + l16 * 32);
                const short8 a1 = *(const short8*)(ps + (16 + l16) * 32);
                if (kk & 1) {
                    a0b = __builtin_amdgcn_mfma_f32_16x16x32_bf16(a0, wif[kk], a0b, 0, 0, 0);
                    a1b = __builtin_amdgcn_mfma_f32_16x16x32_bf16(a1, wif[kk], a1b, 0, 0, 0);
                } else {
                    a0a = __builtin_amdgcn_mfma_f32_16x16x32_bf16(a0, wif[kk], a0a, 0, 0, 0);
                    a1a = __builtin_amdgcn_mfma_f32_16x16x32_bf16(a1, wif[kk], a1a, 0, 0, 0);
                }
            }
            if (tid == 0) {
                const uint32 target = (uint32)NBLK * (uint32)(t + 1);
                while (__hip_atomic_load(ctr, __ATOMIC_RELAXED, __HIP_MEMORY_SCOPE_AGENT) < target) {
                    __builtin_amdgcn_s_sleep(1);
                }
                __threadfence();
            }
            __syncthreads();
        }
    }
}

// ---------------------------------------------------------------------------
extern "C" void kernel_launch(void* const* d_in, const int* in_sizes, int n_in,
                              void* d_out, int out_size, void* d_ws, size_t ws_size,
                              hipStream_t stream)
{
    const float* x    = (const float*)d_in[0];  // [32,512,1024] f32
    const float* wih  = (const float*)d_in[1];  // [1024,4096] f32
    const float* whh  = (const float*)d_in[2];  // [1024,4096] f32
    const float* bias = (const float*)d_in[3];  // [4096] f32
    float* out = (float*)d_out;
    char* ws = (char*)d_ws;

    if (ws_size >= WS_NEED) {
        ushort_t* xproj = (ushort_t*)(ws + XPROJ_OFF);
        ushort_t* wtih  = (ushort_t*)(ws + WTIH_OFF);
        ushort_t* wthh  = (ushort_t*)(ws + WTHH_OFF);
        ull_t*    h0    = (ull_t*)(ws + H0T_OFF);
        ull_t*    h1    = (ull_t*)(ws + H1T_OFF);

        hipLaunchKernelGGL(transpose_cvt, dim3(2048), dim3(256), 0, stream, wih, wtih);
        hipLaunchKernelGGL(transpose_cvt, dim3(2048), dim3(256), 0, stream, whh, wthh);
        hipLaunchKernelGGL(gemm_xproj, dim3(32, 128), dim3(256), 0, stream,
                           x, wtih, bias, xproj);
        // wtih is dead after gemm_xproj: zero-init tagged h buffers in its place
        // (tag 0 == expected tag at t=0, value bf16 0.0 == initial h state)
        hipMemsetAsync(ws + H0T_OFF, 0, 262144, stream);
        hipLaunchKernelGGL(lstm_scan_xp, dim3(NBLK), dim3(512), 0, stream,
                           xproj, wthh, h0, h1, out);
    } else {
        ushort_t* h0  = (ushort_t*)(ws + H0_OFF);
        ushort_t* h1  = (ushort_t*)(ws + H1_OFF);
        uint32*   ctr = (uint32*)(ws + CTR_OFF);

        hipMemsetAsync(ws, 0, 131072 + 256, stream);
        hipLaunchKernelGGL(lstm_scan_fused, dim3(NBLK), dim3(512), 0, stream,
                           x, wih, whh, bias, h0, h1, out, ctr);
    }
}

// Round 5
// 2525.435 us; speedup vs baseline: 1.6529x; 1.6529x over previous
//
#include <hip/hip_runtime.h>

typedef unsigned short ushort_t;
typedef unsigned int   uint32;
typedef unsigned long long ull_t;
typedef __attribute__((ext_vector_type(8))) short short8;   // 8 x bf16 (4 VGPRs)
typedef __attribute__((ext_vector_type(4))) float floatx4;  // MFMA 16x16 accum

#define B_    32
#define T_    512
#define H_    1024
#define G4_   4096
#define HSEQ_ (B_*T_*H_)     // 16777216

#define NBLK 64

// ---- ws layout, xproj path (requires ws_size >= WS_NEED) ----
#define XPROJ_OFF 0ul                 // bf16 [16384][4096] = 134217728
#define WTIH_OFF  134217728ul         // bf16 [4096][1024]  = 8388608 (dead after
                                      //   gemm_xproj -> reused for per-wave flags)
#define WTHH_OFF  142606336ul         // bf16 [4096][1024]  = 8388608
#define H0X_OFF   150994944ul         // bf16 frag-layout   = 65536
#define H1X_OFF   151060480ul         // bf16 frag-layout   = 65536
#define FLAGS8_OFF WTIH_OFF           // 64 blk x 8 waves x 64B = 32768
#define WS_NEED   151130112ul         // unchanged

// ---- ws layout, fallback path (R4) ----
#define H0_OFF  0ul
#define H1_OFF  65536ul
#define CTR_OFF 131072ul

__device__ __forceinline__ ushort_t f2b_rne(float f) {
    uint32 u = __float_as_uint(f);
    u += 0x7fffu + ((u >> 16) & 1u);      // round-to-nearest-even
    return (ushort_t)(u >> 16);
}
__device__ __forceinline__ float b2f(ushort_t u) { return __uint_as_float(((uint32)u) << 16); }
__device__ __forceinline__ float sigm(float x)  { return 1.f / (1.f + __expf(-x)); }
__device__ __forceinline__ float tanh_(float x) { return 1.f - 2.f / (__expf(2.f * x) + 1.f); }

// ---------------------------------------------------------------------------
// Transpose+convert: in fp32 [1024 k][4096 n] -> out bf16 [4096 n][1024 k].
// ---------------------------------------------------------------------------
__global__ void transpose_cvt(const float* __restrict__ in, ushort_t* __restrict__ out)
{
    const int id = blockIdx.x * 256 + threadIdx.x;    // 524288 total
    const int n  = id & 4095;
    const int k0 = (id >> 12) * 8;
    union { ushort_t v[8]; uint4 q; } r;
#pragma unroll
    for (int j = 0; j < 8; j++)
        r.v[j] = f2b_rne(in[(size_t)(k0 + j) * G4_ + n]);
    *(uint4*)(out + (size_t)n * 1024 + k0) = r.q;
}

// ---------------------------------------------------------------------------
// xproj GEMM: xproj[m][n] = bf16( sum_k x[m][k]*W_ih[k][n] + bias[n] )
// ---------------------------------------------------------------------------
__launch_bounds__(256, 2)
__global__ void gemm_xproj(const float* __restrict__ A, const ushort_t* __restrict__ Bt,
                           const float* __restrict__ bias, ushort_t* __restrict__ C)
{
    __shared__ ushort_t As[128 * 32];
    __shared__ ushort_t Bs[128 * 32];
    const int tid = threadIdx.x;
    const int wave = tid >> 6, lane = tid & 63, l16 = lane & 15, quad = lane >> 4;
    const int wm = (wave >> 1) * 64, wn = (wave & 1) * 64;
    const int m0 = blockIdx.y * 128, n0 = blockIdx.x * 128;
    const int r = tid >> 2;               // 0..63 (staging row)
    const int kp = (tid & 3) * 8;         // 0..24 step 8

    floatx4 acc[4][4];
#pragma unroll
    for (int i = 0; i < 4; i++)
#pragma unroll
        for (int j = 0; j < 4; j++) acc[i][j] = (floatx4){0.f, 0.f, 0.f, 0.f};

    for (int kk = 0; kk < 1024; kk += 32) {
#pragma unroll
        for (int h = 0; h < 2; h++) {
            const float* ap = A + (size_t)(m0 + r + h * 64) * 1024 + kk + kp;
            const uint4 u0 = *(const uint4*)ap;
            const uint4 u1 = *(const uint4*)(ap + 4);
            uint4 p;
            p.x = __builtin_amdgcn_perm(u0.y, u0.x, 0x07060302u);
            p.y = __builtin_amdgcn_perm(u0.w, u0.z, 0x07060302u);
            p.z = __builtin_amdgcn_perm(u1.y, u1.x, 0x07060302u);
            p.w = __builtin_amdgcn_perm(u1.w, u1.z, 0x07060302u);
            *(uint4*)&As[(r + h * 64) * 32 + kp] = p;
        }
        const ushort_t* bp = Bt + (size_t)(n0 + r) * 1024 + kk + kp;
        *(uint4*)&Bs[r * 32 + kp]        = *(const uint4*)bp;
        *(uint4*)&Bs[(r + 64) * 32 + kp] = *(const uint4*)(bp + 64 * 1024);
        __syncthreads();

        short8 af[4], bfr[4];
#pragma unroll
        for (int i = 0; i < 4; i++) af[i]  = *(const short8*)&As[(wm + i * 16 + l16) * 32 + quad * 8];
#pragma unroll
        for (int j = 0; j < 4; j++) bfr[j] = *(const short8*)&Bs[(wn + j * 16 + l16) * 32 + quad * 8];
#pragma unroll
        for (int i = 0; i < 4; i++)
#pragma unroll
            for (int j = 0; j < 4; j++)
                acc[i][j] = __builtin_amdgcn_mfma_f32_16x16x32_bf16(af[i], bfr[j], acc[i][j], 0, 0, 0);
        __syncthreads();
    }

#pragma unroll
    for (int i = 0; i < 4; i++) {
        const int gm = m0 + wm + i * 16 + quad * 4;
#pragma unroll
        for (int j = 0; j < 4; j++) {
            const int gn = n0 + wn + j * 16 + l16;
            const float bv = bias[gn];
#pragma unroll
            for (int rr = 0; rr < 4; rr++)
                C[(size_t)(gm + rr) * G4_ + gn] = f2b_rne(acc[i][j][rr] + bv);
        }
    }
}

// ---------------------------------------------------------------------------
// Scan v8 (xproj path). 64 blocks x 512 thr (8 waves). v5 compute structure
// (K-half waves: gate g=w&3, K-half kh=w>>2, 16 reg W_hh frags) with a
// trimmed latency chain:
//   * PER-WAVE publish: each wave drains its own packed-h agent store
//     (s_waitcnt vmcnt(0)) and lane0 immediately stores flags8[bid*8+wave]
//     = t+1. No pre-flag __syncthreads, no tid0 broadcast hop.
//   * Consumer wave polls all 64 source-wave flags (8 src blocks x 8 waves)
//     with ONE 64-lane load + ballot per iteration (32B/wave bytes, cheap).
//   * HALF-BLOCK stage barrier: waves 0-3 stage+consume K rows 0..511
//     (blocks 0..31), waves 4-7 the rest; per-half LDS release/acquire
//     counter replaces full sync#1, so the faster half enters its GEMM
//     without waiting on the slower half's remote sources.
//   * Gate-exchange LDS is parity double-buffered -> exactly ONE full
//     __syncthreads per step (after gate writes).
// Safety induction (unchanged from v5): a block writes h_{t+1} only after
// its full-sync, which requires all 8 waves to pass their poll at t, which
// requires every block/wave to have published h_t, which implies everyone
// finished staging h_{t-1} (same parity buffer). Flags (2KB live, 64B
// stride) live in the dead wtih region, memset after gemm_xproj.
// ---------------------------------------------------------------------------
__launch_bounds__(512, 2)
__global__ void lstm_scan_xp(const ushort_t* __restrict__ xproj, // [16384][4096] bf16
                             const ushort_t* __restrict__ wthh,  // [4096][1024] bf16
                             ushort_t* __restrict__ h0buf,       // bf16 frag-layout
                             ushort_t* __restrict__ h1buf,
                             float* __restrict__ out,            // f32: hseq|h_T|c_T
                             uint32* __restrict__ flags8)        // [64*8], stride 16
{
    const int tid  = threadIdx.x;
    const int bid  = blockIdx.x;
    const int wave = tid >> 6, lane = tid & 63, l16 = lane & 15, quad = lane >> 4;
    const int g     = wave & 3;
    const int khalf = wave >> 2;
    const int unit0 = bid * 16;
    const int col0  = g * 1024 + unit0 + l16;

    __shared__ ushort_t hs[32 * 1024];        // staged h-state, XOR-swizzled
    __shared__ float    gbuf[2][2][4 * 32 * 17]; // [parity][khalf][gate partials]
    __shared__ uint32   hctr[2];              // per-half monotonic arrive ctr

    // one-time: W_hh B-frags from transposed bf16 weights (16B vector loads)
    short8 whf[16];
#pragma unroll
    for (int kk = 0; kk < 16; kk++)
        whf[kk] = *(const short8*)(wthh + (size_t)col0 * 1024 + khalf * 512 + kk * 32 + quad * 8);

    if (tid == 0) { hctr[0] = 0; hctr[1] = 0; }

    const int eb = tid >> 4, ej = tid & 15;
    const int hwoff = (bid >> 1) * 1024 + eb * 32 + 16 * (bid & 1) + ej; // frag layout
    float cst = 0.f;

    // swizzled LDS byte offsets for the two A-frag reads of this lane
    const int b0 = l16, b1 = l16 + 16;
    const int off0 = (b0 * 64 + quad * 16) ^ ((b0 & 7) << 4);
    const int off1 = (b1 * 64 + quad * 16) ^ ((b1 & 7) << 4);
    const int rowbase = khalf * 16 * 2048;   // byte offset of this wave's K-half

    // staging geometry: wave w stages source blocks [8w, 8w+8)
    const int src0  = wave * 8;
    const int abase = (lane >> 1) * 64 + (lane & 1) * 16;

    // prefetch xproj gate values for t=0
    ushort_t xq[4];
    {
        const ushort_t* xp = xproj + ((size_t)eb * T_ + 0) * G4_ + unit0 + ej;
#pragma unroll
        for (int gg = 0; gg < 4; gg++) xq[gg] = xp[gg * 1024];
    }

    __syncthreads();   // hctr init visible

    for (int t = 0; t < 512; t++) {
        const ushort_t* hr = (t & 1) ? h1buf : h0buf;
        ushort_t*       hw = (t & 1) ? h0buf : h1buf;

        // ---- 1. poll: 64 source-wave flags in one 64-lane sweep
        {
            const uint32* fp = flags8 + (size_t)(src0 * 8 + lane) * 16;
            uint32 v;
            do {
                v = __hip_atomic_load(fp, __ATOMIC_RELAXED, __HIP_MEMORY_SCOPE_AGENT);
            } while (__ballot(v >= (uint32)t) != ~0ull);
        }

        // ---- 2. stage 8 x 1KB: issue all 16 agent-loads, then LDS writes
        {
            ull_t d0[8], d1[8];
#pragma unroll
            for (int sl = 0; sl < 8; sl++) {
                const int S = src0 + sl;
                const size_t a = (size_t)(S >> 1) * 2048 + (size_t)((S & 1) * 32 + abase);
                const char* p = (const char*)hr + a;
                d0[sl] = __hip_atomic_load((const ull_t*)p,
                                           __ATOMIC_RELAXED, __HIP_MEMORY_SCOPE_AGENT);
                d1[sl] = __hip_atomic_load((const ull_t*)(p + 8),
                                           __ATOMIC_RELAXED, __HIP_MEMORY_SCOPE_AGENT);
            }
#pragma unroll
            for (int sl = 0; sl < 8; sl++) {
                const int S = src0 + sl;
                const int c = ((S >> 1) * 2048 + (S & 1) * 32 + abase) >> 4;
                const int dst = (c * 16) ^ (((c >> 2) & 7) << 4);
                uint4 v;
                *(ull_t*)&v.x = d0[sl];
                *(ull_t*)&v.z = d1[sl];
                *(uint4*)((char*)hs + dst) = v;
            }
        }

        // ---- 3. per-half arrive/spin barrier (release stage writes)
        if (lane == 0)
            __hip_atomic_fetch_add(&hctr[khalf], 1u,
                                   __ATOMIC_RELEASE, __HIP_MEMORY_SCOPE_WORKGROUP);
        while (__hip_atomic_load(&hctr[khalf],
                                 __ATOMIC_ACQUIRE, __HIP_MEMORY_SCOPE_WORKGROUP)
               < 4u * (uint32)(t + 1)) {}

        // ---- 4. h-GEMM from LDS (bank-uniform ds_read_b128), own K-half only
        floatx4 a0a = (floatx4){0.f, 0.f, 0.f, 0.f};
        floatx4 a0b = a0a, a1a = a0a, a1b = a0a;
#pragma unroll
        for (int kk = 0; kk < 16; kk++) {
            const char* base = (const char*)hs + rowbase + kk * 2048;
            const short8 a0 = *(const short8*)(base + off0);
            const short8 a1 = *(const short8*)(base + off1);
            if (kk & 1) {
                a0b = __builtin_amdgcn_mfma_f32_16x16x32_bf16(a0, whf[kk], a0b, 0, 0, 0);
                a1b = __builtin_amdgcn_mfma_f32_16x16x32_bf16(a1, whf[kk], a1b, 0, 0, 0);
            } else {
                a0a = __builtin_amdgcn_mfma_f32_16x16x32_bf16(a0, whf[kk], a0a, 0, 0, 0);
                a1a = __builtin_amdgcn_mfma_f32_16x16x32_bf16(a1, whf[kk], a1a, 0, 0, 0);
            }
        }
        const floatx4 s0 = a0a + a0b;
        const floatx4 s1 = a1a + a1b;

        // ---- 5. write gate partials to parity buffer
        float* gd = &gbuf[t & 1][khalf][0];
#pragma unroll
        for (int rr = 0; rr < 4; rr++) {
            gd[(g * 32 + quad * 4 + rr) * 17 + l16]      = s0[rr];
            gd[(g * 32 + 16 + quad * 4 + rr) * 17 + l16] = s1[rr];
        }
        __syncthreads();   // the ONE full barrier per step

        // ---- 6. elementwise: thread -> (batch eb, unit ej)
        const float* gA_ = &gbuf[t & 1][0][0];
        const float* gB_ = &gbuf[t & 1][1][0];
        float hval, cval;
        {
            const float gi = gA_[(0 * 32 + eb) * 17 + ej] + gB_[(0 * 32 + eb) * 17 + ej] + b2f(xq[0]);
            const float gf = gA_[(1 * 32 + eb) * 17 + ej] + gB_[(1 * 32 + eb) * 17 + ej] + b2f(xq[1]);
            const float gg = gA_[(2 * 32 + eb) * 17 + ej] + gB_[(2 * 32 + eb) * 17 + ej] + b2f(xq[2]);
            const float go = gA_[(3 * 32 + eb) * 17 + ej] + gB_[(3 * 32 + eb) * 17 + ej] + b2f(xq[3]);
            const float iv = sigm(gi);
            const float fv = sigm(gf);
            const float gv = tanh_(gg);
            const float ov = sigm(go);
            cval = fv * cst + iv * gv;
            cst = cval;
            hval = ov * tanh_(cval);
        }

        if (t < 511) {
            // ---- 7. per-wave publish: packed pair store -> drain -> wave flag
            {
                const uint32 myb = (uint32)f2b_rne(hval);
                const uint32 nbb = (uint32)__shfl_xor((int)myb, 1);
                if ((ej & 1) == 0)
                    __hip_atomic_store((uint32*)(hw + hwoff), myb | (nbb << 16),
                                       __ATOMIC_RELAXED, __HIP_MEMORY_SCOPE_AGENT);
            }
            asm volatile("s_waitcnt vmcnt(0)" ::: "memory");
            if (lane == 0)
                __hip_atomic_store(&flags8[(size_t)(bid * 8 + wave) * 16],
                                   (uint32)(t + 1),
                                   __ATOMIC_RELAXED, __HIP_MEMORY_SCOPE_AGENT);
            // off-path: hseq store + next-step xproj prefetch (hide under polls)
            out[((size_t)eb * T_ + t) * H_ + unit0 + ej] = hval;
            {
                const ushort_t* xp = xproj + ((size_t)eb * T_ + (t + 1)) * G4_ + unit0 + ej;
#pragma unroll
                for (int gg = 0; gg < 4; gg++) xq[gg] = xp[gg * 1024];
            }
        } else {
            out[((size_t)eb * T_ + t) * H_ + unit0 + ej] = hval;
            out[HSEQ_ + eb * H_ + unit0 + ej] = hval;
            out[HSEQ_ + B_ * H_ + eb * H_ + unit0 + ej] = cval;
        }
    }
}

// ---------------------------------------------------------------------------
// Fallback (ws too small for xproj): R4 kernel, verbatim.
// ---------------------------------------------------------------------------
__launch_bounds__(512, 2)
__global__ void lstm_scan_fused(const float* __restrict__ x,
                                const float* __restrict__ wih,
                                const float* __restrict__ whh,
                                const float* __restrict__ bias,
                                ushort_t* __restrict__ h0buf,
                                ushort_t* __restrict__ h1buf,
                                float* __restrict__ out,
                                uint32* __restrict__ ctr)
{
    const int tid  = threadIdx.x;
    const int bid  = blockIdx.x;
    const int wave = tid >> 6, lane = tid & 63, l16 = lane & 15, quad = lane >> 4;
    const int g     = wave & 3;
    const int khalf = wave >> 2;
    const int unit0 = bid * 16;
    const int col0  = g * 1024 + unit0 + l16;
    const int kbase = khalf * 512;

    __shared__ ushort_t xs[32 * 1024];
    __shared__ float gA[4 * 32 * 17];
    __shared__ float gB[4 * 32 * 17];

    short8 wif[16], whf[16];
#pragma unroll
    for (int kk = 0; kk < 16; kk++) {
        short8 vi, vh;
#pragma unroll
        for (int j = 0; j < 8; j++) {
            const size_t k = (size_t)(kbase + kk * 32 + quad * 8 + j);
            vi[j] = (short)f2b_rne(wih[k * G4_ + col0]);
            vh[j] = (short)f2b_rne(whh[k * G4_ + col0]);
        }
        wif[kk] = vi;
        whf[kk] = vh;
    }
    const float bcol = (khalf == 0) ? bias[col0] : 0.f;

    const int eb = tid >> 4, ej = tid & 15;
    const int hwoff = (bid >> 1) * 1024 + eb * 32 + 16 * (bid & 1) + ej;
    float cst = 0.f;

    floatx4 a0a, a0b, a1a, a1b;

    {
        const int sb = tid >> 4, sc = tid & 15;
        const float* xrow = x + ((size_t)sb * T_ + 0) * H_ + sc * 64;
#pragma unroll
        for (int q = 0; q < 8; q++) {
            const uint4 u0 = *(const uint4*)(xrow + q * 8);
            const uint4 u1 = *(const uint4*)(xrow + q * 8 + 4);
            uint4 p;
            p.x = __builtin_amdgcn_perm(u0.y, u0.x, 0x07060302u);
            p.y = __builtin_amdgcn_perm(u0.w, u0.z, 0x07060302u);
            p.z = __builtin_amdgcn_perm(u1.y, u1.x, 0x07060302u);
            p.w = __builtin_amdgcn_perm(u1.w, u1.z, 0x07060302u);
            const int k = sc * 64 + q * 8;
            *(uint4*)&xs[(k >> 5) * 1024 + sb * 32 + (k & 31)] = p;
        }
    }
    __syncthreads();
    a0a = (floatx4){bcol, bcol, bcol, bcol};
    a1a = a0a;
    a0b = (floatx4){0.f, 0.f, 0.f, 0.f};
    a1b = a0b;
#pragma unroll
    for (int kk = 0; kk < 16; kk++) {
        const ushort_t* ps = &xs[(khalf * 16 + kk) * 1024 + quad * 8];
        const short8 a0 = *(const short8*)(ps + l16 * 32);
        const short8 a1 = *(const short8*)(ps + (16 + l16) * 32);
        if (kk & 1) {
            a0b = __builtin_amdgcn_mfma_f32_16x16x32_bf16(a0, wif[kk], a0b, 0, 0, 0);
            a1b = __builtin_amdgcn_mfma_f32_16x16x32_bf16(a1, wif[kk], a1b, 0, 0, 0);
        } else {
            a0a = __builtin_amdgcn_mfma_f32_16x16x32_bf16(a0, wif[kk], a0a, 0, 0, 0);
            a1a = __builtin_amdgcn_mfma_f32_16x16x32_bf16(a1, wif[kk], a1a, 0, 0, 0);
        }
    }

    for (int t = 0; t < 512; t++) {
        const ushort_t* hr = (t & 1) ? h1buf : h0buf;
        ushort_t*       hw = (t & 1) ? h0buf : h1buf;

#pragma unroll
        for (int kk = 0; kk < 16; kk++) {
            const ushort_t* pa = hr + (khalf * 16 + kk) * 1024 + quad * 8;
            const short8 a0 = *(const short8*)(pa + l16 * 32);
            const short8 a1 = *(const short8*)(pa + (16 + l16) * 32);
            if (kk & 1) {
                a0b = __builtin_amdgcn_mfma_f32_16x16x32_bf16(a0, whf[kk], a0b, 0, 0, 0);
                a1b = __builtin_amdgcn_mfma_f32_16x16x32_bf16(a1, whf[kk], a1b, 0, 0, 0);
            } else {
                a0a = __builtin_amdgcn_mfma_f32_16x16x32_bf16(a0, whf[kk], a0a, 0, 0, 0);
                a1a = __builtin_amdgcn_mfma_f32_16x16x32_bf16(a1, whf[kk], a1a, 0, 0, 0);
            }
        }
        const floatx4 s0 = a0a + a0b;
        const floatx4 s1 = a1a + a1b;
        float* gd = khalf ? gB : gA;
#pragma unroll
        for (int rr = 0; rr < 4; rr++) {
            gd[(g * 32 + quad * 4 + rr) * 17 + l16]      = s0[rr];
            gd[(g * 32 + 16 + quad * 4 + rr) * 17 + l16] = s1[rr];
        }
        __syncthreads();

        {
            const float gi = gA[(0 * 32 + eb) * 17 + ej] + gB[(0 * 32 + eb) * 17 + ej];
            const float gf = gA[(1 * 32 + eb) * 17 + ej] + gB[(1 * 32 + eb) * 17 + ej];
            const float gg = gA[(2 * 32 + eb) * 17 + ej] + gB[(2 * 32 + eb) * 17 + ej];
            const float go = gA[(3 * 32 + eb) * 17 + ej] + gB[(3 * 32 + eb) * 17 + ej];
            const float iv = sigm(gi);
            const float fv = sigm(gf);
            const float gv = tanh_(gg);
            const float ov = sigm(go);
            const float c = fv * cst + iv * gv;
            cst = c;
            const float h = ov * tanh_(c);
            hw[hwoff] = f2b_rne(h);
            out[((size_t)eb * T_ + t) * H_ + unit0 + ej] = h;
            if (t == 511) {
                out[HSEQ_ + eb * H_ + unit0 + ej] = h;
                out[HSEQ_ + B_ * H_ + eb * H_ + unit0 + ej] = cst;
            }
        }
        __syncthreads();

        if (t < 511) {
            if (tid == 0) {
                __threadfence();
                __hip_atomic_fetch_add(ctr, 1u, __ATOMIC_RELAXED, __HIP_MEMORY_SCOPE_AGENT);
            }
            {
                const int sb = tid >> 4, sc = tid & 15;
                const float* xrow = x + ((size_t)sb * T_ + (t + 1)) * H_ + sc * 64;
#pragma unroll
                for (int q = 0; q < 8; q++) {
                    const uint4 u0 = *(const uint4*)(xrow + q * 8);
                    const uint4 u1 = *(const uint4*)(xrow + q * 8 + 4);
                    uint4 p;
                    p.x = __builtin_amdgcn_perm(u0.y, u0.x, 0x07060302u);
                    p.y = __builtin_amdgcn_perm(u0.w, u0.z, 0x07060302u);
                    p.z = __builtin_amdgcn_perm(u1.y, u1.x, 0x07060302u);
                    p.w = __builtin_amdgcn_perm(u1.w, u1.z, 0x07060302u);
                    const int k = sc * 64 + q * 8;
                    *(uint4*)&xs[(k >> 5) * 1024 + sb * 32 + (k & 31)] = p;
                }
            }
            __syncthreads();
            a0a = (floatx4){bcol, bcol, bcol, bcol};
            a1a = a0a;
            a0b = (floatx4){0.f, 0.f, 0.f, 0.f};
            a1b = a0b;
#pragma unroll
            for (int kk = 0; kk < 16; kk++) {
                const ushort_t* ps = &xs[(khalf * 16 + kk) * 1024 + quad * 8];
                const short8 a0 = *(const short8*)(ps + l16 * 32);
                const short8 a1 = *(const short8*)(ps + (16 + l16) * 32);
                if (kk & 1) {
                    a0b = __builtin_amdgcn_mfma_f32_16x16x32_bf16(a0, wif[kk], a0b, 0, 0, 0);
                    a1b = __builtin_amdgcn_mfma_f32_16x16x32_bf16(a1, wif[kk], a1b, 0, 0, 0);
                } else {
                    a0a = __builtin_amdgcn_mfma_f32_16x16x32_bf16(a0, wif[kk], a0a, 0, 0, 0);
                    a1a = __builtin_amdgcn_mfma_f32_16x16x32_bf16(a1, wif[kk], a1a, 0, 0, 0);
                }
            }
            if (tid == 0) {
                const uint32 target = (uint32)NBLK * (uint32)(t + 1);
                while (__hip_atomic_load(ctr, __ATOMIC_RELAXED, __HIP_MEMORY_SCOPE_AGENT) < target) {
                    __builtin_amdgcn_s_sleep(1);
                }
                __threadfence();
            }
            __syncthreads();
        }
    }
}

// ---------------------------------------------------------------------------
extern "C" void kernel_launch(void* const* d_in, const int* in_sizes, int n_in,
                              void* d_out, int out_size, void* d_ws, size_t ws_size,
                              hipStream_t stream)
{
    const float* x    = (const float*)d_in[0];  // [32,512,1024] f32
    const float* wih  = (const float*)d_in[1];  // [1024,4096] f32
    const float* whh  = (const float*)d_in[2];  // [1024,4096] f32
    const float* bias = (const float*)d_in[3];  // [4096] f32
    float* out = (float*)d_out;
    char* ws = (char*)d_ws;

    if (ws_size >= WS_NEED) {
        ushort_t* xproj  = (ushort_t*)(ws + XPROJ_OFF);
        ushort_t* wtih   = (ushort_t*)(ws + WTIH_OFF);
        ushort_t* wthh   = (ushort_t*)(ws + WTHH_OFF);
        ushort_t* h0     = (ushort_t*)(ws + H0X_OFF);
        ushort_t* h1     = (ushort_t*)(ws + H1X_OFF);
        uint32*   flags8 = (uint32*)(ws + FLAGS8_OFF);

        hipMemsetAsync(ws + H0X_OFF, 0, 2 * 65536, stream);
        hipLaunchKernelGGL(transpose_cvt, dim3(2048), dim3(256), 0, stream, wih, wtih);
        hipLaunchKernelGGL(transpose_cvt, dim3(2048), dim3(256), 0, stream, whh, wthh);
        hipLaunchKernelGGL(gemm_xproj, dim3(32, 128), dim3(256), 0, stream,
                           x, wtih, bias, xproj);
        // wtih dead after gemm_xproj: per-wave flags live there (zeroed)
        hipMemsetAsync(ws + FLAGS8_OFF, 0, 32768, stream);
        hipLaunchKernelGGL(lstm_scan_xp, dim3(NBLK), dim3(512), 0, stream,
                           xproj, wthh, h0, h1, out, flags8);
    } else {
        ushort_t* h0  = (ushort_t*)(ws + H0_OFF);
        ushort_t* h1  = (ushort_t*)(ws + H1_OFF);
        uint32*   ctr = (uint32*)(ws + CTR_OFF);

        hipMemsetAsync(ws, 0, 131072 + 256, stream);
        hipLaunchKernelGGL(lstm_scan_fused, dim3(NBLK), dim3(512), 0, stream,
                           x, wih, whh, bias, h0, h1, out, ctr);
    }
}